// Round 1
// baseline (917.469 us; speedup 1.0000x reference)
//
#include <hip/hip_runtime.h>
#include <hip/hip_bf16.h>

#define N_NODES 50000
#define N_EDGES 800000
#define IN_F    128
#define HID     16
#define HEADS   8
#define F1      128   // HEADS*HID
#define CLS     40
#define NEG     0.2f

// ---------- helpers ----------
__device__ __forceinline__ unsigned flipf(float f) {
    unsigned u = __float_as_uint(f);
    return (u & 0x80000000u) ? ~u : (u | 0x80000000u);
}
// sentinel 0u == "never touched" -> 0.0f (matches reference isfinite->0 rule)
__device__ __forceinline__ float unflip_or_zero(unsigned u) {
    if (u == 0u) return 0.0f;
    return (u & 0x80000000u) ? __uint_as_float(u & 0x7fffffffu) : __uint_as_float(~u);
}
__device__ __forceinline__ float leaky(float v) { return v >= 0.0f ? v : NEG * v; }

// ---------- kernels ----------
__global__ void zero_kernel(float* __restrict__ p, int n) {
    int i = blockIdx.x * blockDim.x + threadIdx.x;
    if (i < n) p[i] = 0.0f;
}

// X[N,128] @ W[128,128] -> out[N,128]; 8 rows per block, 256 threads
__global__ void gemm1_kernel(const float* __restrict__ X, const float* __restrict__ W,
                             float* __restrict__ out) {
    __shared__ float xs[8][IN_F];
    int rowbase = blockIdx.x * 8;
    int tid = threadIdx.x;
    for (int i = tid; i < 8 * IN_F; i += 256) {
        int r = i >> 7, c = i & 127;
        xs[r][c] = X[(size_t)(rowbase + r) * IN_F + c];
    }
    __syncthreads();
    int col = tid & 127;
    int rg  = (tid >> 7) * 4;   // 0 or 4
    float a0 = 0.f, a1 = 0.f, a2 = 0.f, a3 = 0.f;
    for (int k = 0; k < IN_F; ++k) {
        float w = W[k * F1 + col];
        a0 += xs[rg + 0][k] * w;
        a1 += xs[rg + 1][k] * w;
        a2 += xs[rg + 2][k] * w;
        a3 += xs[rg + 3][k] * w;
    }
    out[(size_t)(rowbase + rg + 0) * F1 + col] = a0;
    out[(size_t)(rowbase + rg + 1) * F1 + col] = a1;
    out[(size_t)(rowbase + rg + 2) * F1 + col] = a2;
    out[(size_t)(rowbase + rg + 3) * F1 + col] = a3;
}

// el/er for layer 1: idx over N*HEADS
__global__ void elr1_kernel(const float* __restrict__ feat1,
                            const float* __restrict__ al, const float* __restrict__ ar,
                            float* __restrict__ el, float* __restrict__ er) {
    int idx = blockIdx.x * blockDim.x + threadIdx.x;
    if (idx >= N_NODES * HEADS) return;
    int n = idx >> 3, h = idx & 7;
    const float* f = feat1 + (size_t)n * F1 + h * HID;
    float a = 0.f, b = 0.f;
    #pragma unroll
    for (int d = 0; d < HID; ++d) {
        a += f[d] * al[h * HID + d];
        b += f[d] * ar[h * HID + d];
    }
    el[idx] = a;
    er[idx] = b;
}

__global__ void edge_max1_kernel(const int* __restrict__ src, const int* __restrict__ dst,
                                 const float* __restrict__ el, const float* __restrict__ er,
                                 unsigned* __restrict__ emax) {
    int idx = blockIdx.x * blockDim.x + threadIdx.x;
    if (idx >= N_EDGES * HEADS) return;
    int e = idx >> 3, h = idx & 7;
    int s = src[e], d = dst[e];
    float v = leaky(el[s * HEADS + h] + er[d * HEADS + h]);
    atomicMax(&emax[d * HEADS + h], flipf(v));
}

__global__ void edge_sum1_kernel(const int* __restrict__ src, const int* __restrict__ dst,
                                 const float* __restrict__ el, const float* __restrict__ er,
                                 const unsigned* __restrict__ emax, float* __restrict__ denom) {
    int idx = blockIdx.x * blockDim.x + threadIdx.x;
    if (idx >= N_EDGES * HEADS) return;
    int e = idx >> 3, h = idx & 7;
    int s = src[e], d = dst[e];
    float v = leaky(el[s * HEADS + h] + er[d * HEADS + h]);
    float m = unflip_or_zero(emax[d * HEADS + h]);
    atomicAdd(&denom[d * HEADS + h], expf(v - m));
}

// idx over E*128: 128 consecutive threads = one edge (coalesced feat gather)
__global__ void edge_agg1_kernel(const int* __restrict__ src, const int* __restrict__ dst,
                                 const float* __restrict__ el, const float* __restrict__ er,
                                 const unsigned* __restrict__ emax, const float* __restrict__ denom,
                                 const float* __restrict__ feat1, float* __restrict__ hbuf) {
    long long idx = (long long)blockIdx.x * blockDim.x + threadIdx.x;
    if (idx >= (long long)N_EDGES * F1) return;
    int e = (int)(idx >> 7), j = (int)(idx & 127);
    int h = j >> 4;
    int s = src[e], d = dst[e];
    float v = leaky(el[s * HEADS + h] + er[d * HEADS + h]);
    float m = unflip_or_zero(emax[d * HEADS + h]);
    float alpha = expf(v - m) / (denom[d * HEADS + h] + 1e-9f);
    atomicAdd(&hbuf[(size_t)d * F1 + j], alpha * feat1[(size_t)s * F1 + j]);
}

__global__ void elu_bias_kernel(float* __restrict__ hbuf, const float* __restrict__ b1) {
    int idx = blockIdx.x * blockDim.x + threadIdx.x;
    if (idx >= N_NODES * F1) return;
    float v = hbuf[idx] + b1[idx & 127];
    hbuf[idx] = v > 0.0f ? v : expm1f(v);
}

// h[N,128] @ W2[128,40] -> feat2[N,40]; thread per output
__global__ void gemm2_kernel(const float* __restrict__ H, const float* __restrict__ W2,
                             float* __restrict__ feat2) {
    int idx = blockIdx.x * blockDim.x + threadIdx.x;
    if (idx >= N_NODES * CLS) return;
    int n = idx / CLS, c = idx - n * CLS;
    const float* hr = H + (size_t)n * F1;
    float acc = 0.f;
    for (int k = 0; k < F1; ++k) acc += hr[k] * W2[k * CLS + c];
    feat2[idx] = acc;
}

__global__ void elr2_kernel(const float* __restrict__ feat2,
                            const float* __restrict__ al, const float* __restrict__ ar,
                            float* __restrict__ el, float* __restrict__ er) {
    int n = blockIdx.x * blockDim.x + threadIdx.x;
    if (n >= N_NODES) return;
    const float* f = feat2 + (size_t)n * CLS;
    float a = 0.f, b = 0.f;
    #pragma unroll
    for (int c = 0; c < CLS; ++c) {
        a += f[c] * al[c];
        b += f[c] * ar[c];
    }
    el[n] = a;
    er[n] = b;
}

__global__ void edge_max2_kernel(const int* __restrict__ src, const int* __restrict__ dst,
                                 const float* __restrict__ el, const float* __restrict__ er,
                                 unsigned* __restrict__ emax) {
    int e = blockIdx.x * blockDim.x + threadIdx.x;
    if (e >= N_EDGES) return;
    float v = leaky(el[src[e]] + er[dst[e]]);
    atomicMax(&emax[dst[e]], flipf(v));
}

__global__ void edge_sum2_kernel(const int* __restrict__ src, const int* __restrict__ dst,
                                 const float* __restrict__ el, const float* __restrict__ er,
                                 const unsigned* __restrict__ emax, float* __restrict__ denom) {
    int e = blockIdx.x * blockDim.x + threadIdx.x;
    if (e >= N_EDGES) return;
    int d = dst[e];
    float v = leaky(el[src[e]] + er[d]);
    float m = unflip_or_zero(emax[d]);
    atomicAdd(&denom[d], expf(v - m));
}

// idx over E*40
__global__ void edge_agg2_kernel(const int* __restrict__ src, const int* __restrict__ dst,
                                 const float* __restrict__ el, const float* __restrict__ er,
                                 const unsigned* __restrict__ emax, const float* __restrict__ denom,
                                 const float* __restrict__ feat2, float* __restrict__ out2) {
    long long idx = (long long)blockIdx.x * blockDim.x + threadIdx.x;
    if (idx >= (long long)N_EDGES * CLS) return;
    int e = (int)(idx / CLS), c = (int)(idx - (long long)e * CLS);
    int s = src[e], d = dst[e];
    float v = leaky(el[s] + er[d]);
    float m = unflip_or_zero(emax[d]);
    float alpha = expf(v - m) / (denom[d] + 1e-9f);
    atomicAdd(&out2[(size_t)d * CLS + c], alpha * feat2[(size_t)s * CLS + c]);
}

__global__ void final_kernel(const float* __restrict__ out2, const float* __restrict__ b2,
                             float* __restrict__ out) {
    int idx = blockIdx.x * blockDim.x + threadIdx.x;
    if (idx >= N_NODES * CLS) return;
    int c = idx % CLS;
    out[idx] = out2[idx] + b2[c];
}

// ---------- launch ----------
extern "C" void kernel_launch(void* const* d_in, const int* in_sizes, int n_in,
                              void* d_out, int out_size, void* d_ws, size_t ws_size,
                              hipStream_t stream) {
    const float* features = (const float*)d_in[0];
    const int*   esrc     = (const int*)d_in[1];
    const int*   edst     = (const int*)d_in[2];
    const float* W1       = (const float*)d_in[3];
    const float* al1      = (const float*)d_in[4];
    const float* ar1      = (const float*)d_in[5];
    const float* b1       = (const float*)d_in[6];
    const float* W2       = (const float*)d_in[7];
    const float* al2      = (const float*)d_in[8];
    const float* ar2      = (const float*)d_in[9];
    const float* b2       = (const float*)d_in[10];
    float* out = (float*)d_out;

    float* ws = (float*)d_ws;
    float* feat1  = ws;                   // 6,400,000
    float* hbuf   = ws + 6400000;         // 6,400,000  (accum region start)
    float* out2   = ws + 12800000;        // 2,000,000
    unsigned* emax1 = (unsigned*)(ws + 14800000); // 400,000
    float* denom1 = ws + 15200000;        // 400,000
    unsigned* emax2 = (unsigned*)(ws + 15600000); // 50,000
    float* denom2 = ws + 15650000;        // 50,000   (accum region = 9,300,000 floats)
    float* el1    = ws + 15700000;        // 400,000
    float* er1    = ws + 16100000;        // 400,000
    float* feat2  = ws + 16500000;        // 2,000,000
    float* el2    = ws + 18500000;        // 50,000
    float* er2    = ws + 18550000;        // 50,000  -> total 18,600,000 floats (74.4 MB)

    const int B = 256;
    // zero all accumulators (hbuf..denom2 contiguous)
    {
        int n = 9300000;
        zero_kernel<<<(n + B - 1) / B, B, 0, stream>>>(hbuf, n);
    }
    gemm1_kernel<<<N_NODES / 8, B, 0, stream>>>(features, W1, feat1);
    elr1_kernel<<<(N_NODES * HEADS + B - 1) / B, B, 0, stream>>>(feat1, al1, ar1, el1, er1);
    edge_max1_kernel<<<(N_EDGES * HEADS + B - 1) / B, B, 0, stream>>>(esrc, edst, el1, er1, emax1);
    edge_sum1_kernel<<<(N_EDGES * HEADS + B - 1) / B, B, 0, stream>>>(esrc, edst, el1, er1, emax1, denom1);
    {
        long long n = (long long)N_EDGES * F1; // 102,400,000
        edge_agg1_kernel<<<(int)((n + B - 1) / B), B, 0, stream>>>(esrc, edst, el1, er1, emax1,
                                                                    denom1, feat1, hbuf);
    }
    elu_bias_kernel<<<(N_NODES * F1 + B - 1) / B, B, 0, stream>>>(hbuf, b1);
    gemm2_kernel<<<(N_NODES * CLS + B - 1) / B, B, 0, stream>>>(hbuf, W2, feat2);
    elr2_kernel<<<(N_NODES + B - 1) / B, B, 0, stream>>>(feat2, al2, ar2, el2, er2);
    edge_max2_kernel<<<(N_EDGES + B - 1) / B, B, 0, stream>>>(esrc, edst, el2, er2, emax2);
    edge_sum2_kernel<<<(N_EDGES + B - 1) / B, B, 0, stream>>>(esrc, edst, el2, er2, emax2, denom2);
    {
        long long n = (long long)N_EDGES * CLS; // 32,000,000
        edge_agg2_kernel<<<(int)((n + B - 1) / B), B, 0, stream>>>(esrc, edst, el2, er2, emax2,
                                                                    denom2, feat2, out2);
    }
    final_kernel<<<(N_NODES * CLS + B - 1) / B, B, 0, stream>>>(out2, b2, out);
}

// Round 2
// 430.201 us; speedup vs baseline: 2.1327x; 2.1327x over previous
//
#include <hip/hip_runtime.h>
#include <hip/hip_bf16.h>

#define N_NODES 50000
#define N_EDGES 800000
#define IN_F    128
#define HID     16
#define HEADS   8
#define F1      128   // HEADS*HID
#define CLS     40
#define NEG     0.2f
#define NEG_INF (-__builtin_inff())

__device__ __forceinline__ float leaky(float v) { return v >= 0.0f ? v : NEG * v; }

// ---------------- CSR build ----------------
__global__ void zero_int_kernel(int* __restrict__ p, int n) {
    int i = blockIdx.x * blockDim.x + threadIdx.x;
    if (i < n) p[i] = 0;
}

__global__ void hist_kernel(const int* __restrict__ dst, int* __restrict__ counts) {
    int e = blockIdx.x * blockDim.x + threadIdx.x;
    if (e < N_EDGES) atomicAdd(&counts[dst[e]], 1);
}

// per-block sums of counts (256 per block)
__global__ void reduce_kernel(const int* __restrict__ counts, int* __restrict__ bsum) {
    __shared__ int sm[256];
    int t = threadIdx.x;
    int i = blockIdx.x * 256 + t;
    sm[t] = (i < N_NODES) ? counts[i] : 0;
    __syncthreads();
    for (int off = 128; off > 0; off >>= 1) {
        if (t < off) sm[t] += sm[t + off];
        __syncthreads();
    }
    if (t == 0) bsum[blockIdx.x] = sm[0];
}

// exclusive scan of <=256 block sums (single block)
__global__ void scanb_kernel(const int* __restrict__ bsum, int* __restrict__ bpref, int nb) {
    __shared__ int sm[256];
    int t = threadIdx.x;
    int x = (t < nb) ? bsum[t] : 0;
    sm[t] = x;
    __syncthreads();
    for (int off = 1; off < 256; off <<= 1) {
        int v = (t >= off) ? sm[t - off] : 0;
        __syncthreads();
        sm[t] += v;
        __syncthreads();
    }
    bpref[t] = sm[t] - x;   // exclusive
}

// final scan: offsets[i] (i in [0, N_NODES]) = bpref[b] + block-exclusive
__global__ void scan_kernel(const int* __restrict__ counts, const int* __restrict__ bpref,
                            int* __restrict__ offsets) {
    __shared__ int sm[256];
    int t = threadIdx.x;
    int i = blockIdx.x * 256 + t;
    int x = (i < N_NODES) ? counts[i] : 0;
    sm[t] = x;
    __syncthreads();
    for (int off = 1; off < 256; off <<= 1) {
        int v = (t >= off) ? sm[t - off] : 0;
        __syncthreads();
        sm[t] += v;
        __syncthreads();
    }
    if (i <= N_NODES) offsets[i] = bpref[blockIdx.x] + sm[t] - x;
}

__global__ void scatter_kernel(const int* __restrict__ src, const int* __restrict__ dst,
                               const int* __restrict__ offsets, int* __restrict__ cursor,
                               int* __restrict__ srcs_sorted) {
    int e = blockIdx.x * blockDim.x + threadIdx.x;
    if (e >= N_EDGES) return;
    int d = dst[e];
    int pos = offsets[d] + atomicAdd(&cursor[d], 1);
    srcs_sorted[pos] = src[e];
}

// ---------------- dense kernels ----------------
// X[N,128] @ W[128,128] -> out[N,128]; 8 rows per block, 256 threads
__global__ void gemm1_kernel(const float* __restrict__ X, const float* __restrict__ W,
                             float* __restrict__ out) {
    __shared__ float xs[8][IN_F];
    int rowbase = blockIdx.x * 8;
    int tid = threadIdx.x;
    for (int i = tid; i < 8 * IN_F; i += 256) {
        int r = i >> 7, c = i & 127;
        xs[r][c] = X[(size_t)(rowbase + r) * IN_F + c];
    }
    __syncthreads();
    int col = tid & 127;
    int rg  = (tid >> 7) * 4;
    float a0 = 0.f, a1 = 0.f, a2 = 0.f, a3 = 0.f;
    for (int k = 0; k < IN_F; ++k) {
        float w = W[k * F1 + col];
        a0 += xs[rg + 0][k] * w;
        a1 += xs[rg + 1][k] * w;
        a2 += xs[rg + 2][k] * w;
        a3 += xs[rg + 3][k] * w;
    }
    out[(size_t)(rowbase + rg + 0) * F1 + col] = a0;
    out[(size_t)(rowbase + rg + 1) * F1 + col] = a1;
    out[(size_t)(rowbase + rg + 2) * F1 + col] = a2;
    out[(size_t)(rowbase + rg + 3) * F1 + col] = a3;
}

__global__ void elr1_kernel(const float* __restrict__ feat1,
                            const float* __restrict__ al, const float* __restrict__ ar,
                            float* __restrict__ el, float* __restrict__ er) {
    int idx = blockIdx.x * blockDim.x + threadIdx.x;
    if (idx >= N_NODES * HEADS) return;
    int n = idx >> 3, h = idx & 7;
    const float* f = feat1 + (size_t)n * F1 + h * HID;
    float a = 0.f, b = 0.f;
    #pragma unroll
    for (int d = 0; d < HID; ++d) {
        a += f[d] * al[h * HID + d];
        b += f[d] * ar[h * HID + d];
    }
    el[idx] = a;
    er[idx] = b;
}

// h[N,128] @ W2[128,40] -> feat2[N,40]
__global__ void gemm2_kernel(const float* __restrict__ H, const float* __restrict__ W2,
                             float* __restrict__ feat2) {
    int idx = blockIdx.x * blockDim.x + threadIdx.x;
    if (idx >= N_NODES * CLS) return;
    int n = idx / CLS, c = idx - n * CLS;
    const float* hr = H + (size_t)n * F1;
    float acc = 0.f;
    for (int k = 0; k < F1; ++k) acc += hr[k] * W2[k * CLS + c];
    feat2[idx] = acc;
}

__global__ void elr2_kernel(const float* __restrict__ feat2,
                            const float* __restrict__ al, const float* __restrict__ ar,
                            float* __restrict__ el, float* __restrict__ er) {
    int n = blockIdx.x * blockDim.x + threadIdx.x;
    if (n >= N_NODES) return;
    const float* f = feat2 + (size_t)n * CLS;
    float a = 0.f, b = 0.f;
    #pragma unroll
    for (int c = 0; c < CLS; ++c) {
        a += f[c] * al[c];
        b += f[c] * ar[c];
    }
    el[n] = a;
    er[n] = b;
}

// ---------------- fused GAT layers (one wave per dst node) ----------------
// Layer 1: 8 heads x 16 dims. Lane layout for softmax: lane = slot*8 + h.
// Lane layout for aggregate: lane j covers features j and j+64.
__global__ void gat1_fused(const int* __restrict__ offsets, const int* __restrict__ srcs,
                           const float* __restrict__ el, const float* __restrict__ er,
                           const float* __restrict__ feat1, const float* __restrict__ b1,
                           float* __restrict__ hbuf) {
    int wave = threadIdx.x >> 6;
    int lane = threadIdx.x & 63;
    int d = blockIdx.x * 4 + wave;
    if (d >= N_NODES) return;
    int off = offsets[d];
    int deg = offsets[d + 1] - off;

    int h = lane & 7, slot = lane >> 3;
    float er_d = er[d * 8 + h];

    // online softmax (per-head) over this lane's edge slots
    float m = NEG_INF, l = 0.f;
    for (int base = 0; base < deg; base += 8) {
        int e = base + slot;
        float sc = NEG_INF;
        if (e < deg) {
            int s = srcs[off + e];
            sc = leaky(el[s * 8 + h] + er_d);
        }
        float mn = fmaxf(m, sc);
        float f1 = (m  == NEG_INF) ? 0.f : __expf(m - mn);
        float f2 = (sc == NEG_INF) ? 0.f : __expf(sc - mn);
        l = l * f1 + f2;
        m = mn;
    }
    // reduce across slots (lane bits 3..5)
    #pragma unroll
    for (int mask = 8; mask <= 32; mask <<= 1) {
        float m2 = __shfl_xor(m, mask, 64);
        float l2 = __shfl_xor(l, mask, 64);
        float mn = fmaxf(m, m2);
        float f1 = (m  == NEG_INF) ? 0.f : __expf(m - mn);
        float f2 = (m2 == NEG_INF) ? 0.f : __expf(m2 - mn);
        l = l * f1 + l2 * f2;
        m = mn;
    }
    float inv_l = 1.f / (l + 1e-9f);

    // aggregate: lane covers feature j0=lane (head lane>>4) and j1=lane+64 (head 4+(lane>>4))
    int h0 = lane >> 4;
    int h1 = 4 + h0;
    float acc0 = 0.f, acc1 = 0.f;
    for (int base = 0; base < deg; base += 8) {
        int e = base + slot;
        float alpha = 0.f;
        int s = 0;
        if (e < deg) {
            s = srcs[off + e];
            float sc = leaky(el[s * 8 + h] + er_d);
            alpha = __expf(sc - m) * inv_l;
        }
        int kmax = min(8, deg - base);
        for (int k = 0; k < kmax; ++k) {
            float a0 = __shfl(alpha, k * 8 + h0, 64);
            float a1 = __shfl(alpha, k * 8 + h1, 64);
            int   se = __shfl(s,     k * 8,      64);
            const float* fr = feat1 + (size_t)se * F1;
            acc0 += a0 * fr[lane];
            acc1 += a1 * fr[lane + 64];
        }
    }
    // epilogue: bias + ELU
    float v0 = acc0 + b1[lane];
    float v1 = acc1 + b1[lane + 64];
    hbuf[(size_t)d * F1 + lane]      = v0 > 0.f ? v0 : expm1f(v0);
    hbuf[(size_t)d * F1 + lane + 64] = v1 > 0.f ? v1 : expm1f(v1);
}

// Layer 2: 1 head, 40 classes. Softmax: lane = edge slot (64-wide).
__global__ void gat2_fused(const int* __restrict__ offsets, const int* __restrict__ srcs,
                           const float* __restrict__ el, const float* __restrict__ er,
                           const float* __restrict__ feat2, const float* __restrict__ b2,
                           float* __restrict__ out) {
    int wave = threadIdx.x >> 6;
    int lane = threadIdx.x & 63;
    int d = blockIdx.x * 4 + wave;
    if (d >= N_NODES) return;
    int off = offsets[d];
    int deg = offsets[d + 1] - off;

    float er_d = er[d];

    float m = NEG_INF, l = 0.f;
    for (int base = 0; base < deg; base += 64) {
        int e = base + lane;
        float sc = NEG_INF;
        if (e < deg) {
            int s = srcs[off + e];
            sc = leaky(el[s] + er_d);
        }
        float mn = fmaxf(m, sc);
        float f1 = (m  == NEG_INF) ? 0.f : __expf(m - mn);
        float f2 = (sc == NEG_INF) ? 0.f : __expf(sc - mn);
        l = l * f1 + f2;
        m = mn;
    }
    #pragma unroll
    for (int mask = 1; mask <= 32; mask <<= 1) {
        float m2 = __shfl_xor(m, mask, 64);
        float l2 = __shfl_xor(l, mask, 64);
        float mn = fmaxf(m, m2);
        float f1 = (m  == NEG_INF) ? 0.f : __expf(m - mn);
        float f2 = (m2 == NEG_INF) ? 0.f : __expf(m2 - mn);
        l = l * f1 + l2 * f2;
        m = mn;
    }
    float inv_l = 1.f / (l + 1e-9f);

    float acc = 0.f;
    for (int base = 0; base < deg; base += 64) {
        int e = base + lane;
        float alpha = 0.f;
        int s = 0;
        if (e < deg) {
            s = srcs[off + e];
            float sc = leaky(el[s] + er_d);
            alpha = __expf(sc - m) * inv_l;
        }
        int kmax = min(64, deg - base);
        for (int k = 0; k < kmax; ++k) {
            float a  = __shfl(alpha, k, 64);
            int   se = __shfl(s,     k, 64);
            if (lane < CLS) acc += a * feat2[(size_t)se * CLS + lane];
        }
    }
    if (lane < CLS) out[(size_t)d * CLS + lane] = acc + b2[lane];
}

// ---------------- launch ----------------
extern "C" void kernel_launch(void* const* d_in, const int* in_sizes, int n_in,
                              void* d_out, int out_size, void* d_ws, size_t ws_size,
                              hipStream_t stream) {
    const float* features = (const float*)d_in[0];
    const int*   esrc     = (const int*)d_in[1];
    const int*   edst     = (const int*)d_in[2];
    const float* W1       = (const float*)d_in[3];
    const float* al1      = (const float*)d_in[4];
    const float* ar1      = (const float*)d_in[5];
    const float* b1       = (const float*)d_in[6];
    const float* W2       = (const float*)d_in[7];
    const float* al2      = (const float*)d_in[8];
    const float* ar2      = (const float*)d_in[9];
    const float* b2       = (const float*)d_in[10];
    float* out = (float*)d_out;

    float* ws = (float*)d_ws;
    float* feat1 = ws;                    // 6,400,000
    float* hbuf  = ws + 6400000;          // 6,400,000
    float* feat2 = ws + 12800000;         // 2,000,000
    float* el1   = ws + 14800000;         // 400,000
    float* er1   = ws + 15200000;         // 400,000
    float* el2   = ws + 15600000;         // 50,000
    float* er2   = ws + 15650000;         // 50,000
    int* counts  = (int*)(ws + 15700000); // 50,000
    int* cursor  = (int*)(ws + 15750000); // 50,000  (adjacent to counts for joint zeroing)
    int* offsets = (int*)(ws + 15800000); // 50,001
    int* bsum    = (int*)(ws + 15860000); // 256
    int* bpref   = (int*)(ws + 15861000); // 256
    int* srcs    = (int*)(ws + 15900000); // 800,000  -> total 16.7M floats = 66.8 MB

    const int B = 256;
    const int NB = (N_NODES + 255) / 256;   // 196 blocks for node-sized scans

    // CSR build
    zero_int_kernel<<<(100000 + B - 1) / B, B, 0, stream>>>(counts, 100000); // counts+cursor
    hist_kernel<<<(N_EDGES + B - 1) / B, B, 0, stream>>>(edst, counts);
    reduce_kernel<<<NB, 256, 0, stream>>>(counts, bsum);
    scanb_kernel<<<1, 256, 0, stream>>>(bsum, bpref, NB);
    scan_kernel<<<NB, 256, 0, stream>>>(counts, bpref, offsets);
    scatter_kernel<<<(N_EDGES + B - 1) / B, B, 0, stream>>>(esrc, edst, offsets, cursor, srcs);

    // layer 1
    gemm1_kernel<<<N_NODES / 8, B, 0, stream>>>(features, W1, feat1);
    elr1_kernel<<<(N_NODES * HEADS + B - 1) / B, B, 0, stream>>>(feat1, al1, ar1, el1, er1);
    gat1_fused<<<(N_NODES + 3) / 4, B, 0, stream>>>(offsets, srcs, el1, er1, feat1, b1, hbuf);

    // layer 2
    gemm2_kernel<<<(N_NODES * CLS + B - 1) / B, B, 0, stream>>>(hbuf, W2, feat2);
    elr2_kernel<<<(N_NODES + B - 1) / B, B, 0, stream>>>(feat2, al2, ar2, el2, er2);
    gat2_fused<<<(N_NODES + 3) / 4, B, 0, stream>>>(offsets, srcs, el2, er2, feat2, b2, out);
}

// Round 4
// 369.290 us; speedup vs baseline: 2.4844x; 1.1649x over previous
//
#include <hip/hip_runtime.h>
#include <hip/hip_bf16.h>

#define N_NODES 50000
#define N_EDGES 800000
#define IN_F    128
#define HID     16
#define HEADS   8
#define F1      128   // HEADS*HID
#define CLS     40
#define NEG     0.2f
#define NEG_INF (-__builtin_inff())

typedef __bf16 bf16x8 __attribute__((ext_vector_type(8)));
typedef __bf16 bf16x2 __attribute__((ext_vector_type(2)));
typedef float  f32x4  __attribute__((ext_vector_type(4)));

__device__ __forceinline__ float leaky(float v) { return v >= 0.0f ? v : NEG * v; }

// ---------------- CSR build ----------------
__global__ void zero_int_kernel(int* __restrict__ p, int n) {
    int i = blockIdx.x * blockDim.x + threadIdx.x;
    if (i < n) p[i] = 0;
}

__global__ void hist_kernel(const int* __restrict__ dst, int* __restrict__ counts) {
    int e = blockIdx.x * blockDim.x + threadIdx.x;
    if (e < N_EDGES) atomicAdd(&counts[dst[e]], 1);
}

__global__ void reduce_kernel(const int* __restrict__ counts, int* __restrict__ bsum) {
    __shared__ int sm[256];
    int t = threadIdx.x;
    int i = blockIdx.x * 256 + t;
    sm[t] = (i < N_NODES) ? counts[i] : 0;
    __syncthreads();
    for (int off = 128; off > 0; off >>= 1) {
        if (t < off) sm[t] += sm[t + off];
        __syncthreads();
    }
    if (t == 0) bsum[blockIdx.x] = sm[0];
}

__global__ void scanb_kernel(const int* __restrict__ bsum, int* __restrict__ bpref, int nb) {
    __shared__ int sm[256];
    int t = threadIdx.x;
    int x = (t < nb) ? bsum[t] : 0;
    sm[t] = x;
    __syncthreads();
    for (int off = 1; off < 256; off <<= 1) {
        int v = (t >= off) ? sm[t - off] : 0;
        __syncthreads();
        sm[t] += v;
        __syncthreads();
    }
    bpref[t] = sm[t] - x;   // exclusive
}

__global__ void scan_kernel(const int* __restrict__ counts, const int* __restrict__ bpref,
                            int* __restrict__ offsets) {
    __shared__ int sm[256];
    int t = threadIdx.x;
    int i = blockIdx.x * 256 + t;
    int x = (i < N_NODES) ? counts[i] : 0;
    sm[t] = x;
    __syncthreads();
    for (int off = 1; off < 256; off <<= 1) {
        int v = (t >= off) ? sm[t - off] : 0;
        __syncthreads();
        sm[t] += v;
        __syncthreads();
    }
    if (i <= N_NODES) offsets[i] = bpref[blockIdx.x] + sm[t] - x;
}

__global__ void scatter_kernel(const int* __restrict__ src, const int* __restrict__ dst,
                               const int* __restrict__ offsets, int* __restrict__ cursor,
                               int* __restrict__ srcs_sorted) {
    int e = blockIdx.x * blockDim.x + threadIdx.x;
    if (e >= N_EDGES) return;
    int d = dst[e];
    int pos = offsets[d] + atomicAdd(&cursor[d], 1);
    srcs_sorted[pos] = src[e];
}

// ---------------- bf16 conversion ----------------
__global__ void conv_feat_kernel(const float* __restrict__ X, __bf16* __restrict__ out) {
    int i = blockIdx.x * blockDim.x + threadIdx.x;   // over N*IN_F/4
    if (i >= N_NODES * IN_F / 4) return;
    const float4 v = ((const float4*)X)[i];
    __bf16* o = out + i * 4;
    o[0] = (__bf16)v.x; o[1] = (__bf16)v.y; o[2] = (__bf16)v.z; o[3] = (__bf16)v.w;
}

// W1[k][n] (128x128) -> w1t[n][k] bf16
__global__ void conv_w1t_kernel(const float* __restrict__ W1, __bf16* __restrict__ w1t) {
    int i = blockIdx.x * blockDim.x + threadIdx.x;
    if (i >= 128 * 128) return;
    int n = i >> 7, k = i & 127;
    w1t[i] = (__bf16)W1[k * 128 + n];
}

// W2[k][c] (128x40) -> w2t[n][k] bf16 padded to n<48
__global__ void conv_w2t_kernel(const float* __restrict__ W2, __bf16* __restrict__ w2t) {
    int i = blockIdx.x * blockDim.x + threadIdx.x;
    if (i >= 48 * 128) return;
    int n = i >> 7, k = i & 127;
    w2t[i] = (n < CLS) ? (__bf16)W2[k * CLS + n] : (__bf16)0.0f;
}

// ---------------- MFMA GEMMs ----------------
// featb[N,128]bf16 @ w1t -> feat1b[N,128]bf16. 4 waves/block, 64 rows/block.
__global__ __launch_bounds__(256) void gemm1_mfma(const __bf16* __restrict__ A,
                                                  const __bf16* __restrict__ Wt,
                                                  __bf16* __restrict__ outb) {
    int wave = threadIdx.x >> 6, lane = threadIdx.x & 63;
    int m0 = blockIdx.x * 64 + wave * 16;
    int row = m0 + (lane & 15);
    int rowc = row < N_NODES ? row : N_NODES - 1;   // clamped read; writes guarded
    int ko = (lane >> 4) * 8;

    f32x4 acc[8];
    #pragma unroll
    for (int t = 0; t < 8; ++t)
        #pragma unroll
        for (int r = 0; r < 4; ++r) acc[t][r] = 0.f;

    for (int ks = 0; ks < 128; ks += 32) {
        bf16x8 a = *(const bf16x8*)(A + (size_t)rowc * 128 + ks + ko);
        #pragma unroll
        for (int t = 0; t < 8; ++t) {
            bf16x8 b = *(const bf16x8*)(Wt + (size_t)(t * 16 + (lane & 15)) * 128 + ks + ko);
            acc[t] = __builtin_amdgcn_mfma_f32_16x16x32_bf16(a, b, acc[t], 0, 0, 0);
        }
    }
    int rbase = m0 + (lane >> 4) * 4;
    #pragma unroll
    for (int t = 0; t < 8; ++t) {
        int gcol = t * 16 + (lane & 15);
        #pragma unroll
        for (int r = 0; r < 4; ++r) {
            int grow = rbase + r;
            if (grow < N_NODES) outb[(size_t)grow * 128 + gcol] = (__bf16)acc[t][r];
        }
    }
}

// hbufb[N,128]bf16 @ w2t(48x128) -> feat2[N,40] fp32
__global__ __launch_bounds__(256) void gemm2_mfma(const __bf16* __restrict__ A,
                                                  const __bf16* __restrict__ Wt,
                                                  float* __restrict__ out) {
    int wave = threadIdx.x >> 6, lane = threadIdx.x & 63;
    int m0 = blockIdx.x * 64 + wave * 16;
    int row = m0 + (lane & 15);
    int rowc = row < N_NODES ? row : N_NODES - 1;
    int ko = (lane >> 4) * 8;

    f32x4 acc[3];
    #pragma unroll
    for (int t = 0; t < 3; ++t)
        #pragma unroll
        for (int r = 0; r < 4; ++r) acc[t][r] = 0.f;

    for (int ks = 0; ks < 128; ks += 32) {
        bf16x8 a = *(const bf16x8*)(A + (size_t)rowc * 128 + ks + ko);
        #pragma unroll
        for (int t = 0; t < 3; ++t) {
            bf16x8 b = *(const bf16x8*)(Wt + (size_t)(t * 16 + (lane & 15)) * 128 + ks + ko);
            acc[t] = __builtin_amdgcn_mfma_f32_16x16x32_bf16(a, b, acc[t], 0, 0, 0);
        }
    }
    int rbase = m0 + (lane >> 4) * 4;
    #pragma unroll
    for (int t = 0; t < 3; ++t) {
        int gcol = t * 16 + (lane & 15);
        if (gcol >= CLS) continue;
        #pragma unroll
        for (int r = 0; r < 4; ++r) {
            int grow = rbase + r;
            if (grow < N_NODES) out[(size_t)grow * CLS + gcol] = acc[t][r];
        }
    }
}

// ---------------- attention dot products ----------------
__global__ void elr1_kernel(const __bf16* __restrict__ feat1b,
                            const float* __restrict__ al, const float* __restrict__ ar,
                            float* __restrict__ el, float* __restrict__ er) {
    int idx = blockIdx.x * blockDim.x + threadIdx.x;
    if (idx >= N_NODES * HEADS) return;
    int n = idx >> 3, h = idx & 7;
    const __bf16* f = feat1b + (size_t)n * F1 + h * HID;
    float a = 0.f, b = 0.f;
    #pragma unroll
    for (int d = 0; d < HID; ++d) {
        float v = (float)f[d];
        a += v * al[h * HID + d];
        b += v * ar[h * HID + d];
    }
    el[idx] = a;
    er[idx] = b;
}

__global__ void elr2_kernel(const float* __restrict__ feat2,
                            const float* __restrict__ al, const float* __restrict__ ar,
                            float* __restrict__ el, float* __restrict__ er) {
    int n = blockIdx.x * blockDim.x + threadIdx.x;
    if (n >= N_NODES) return;
    const float* f = feat2 + (size_t)n * CLS;
    float a = 0.f, b = 0.f;
    #pragma unroll
    for (int c = 0; c < CLS; ++c) {
        a += f[c] * al[c];
        b += f[c] * ar[c];
    }
    el[n] = a;
    er[n] = b;
}

// ---------------- fused GAT layers ----------------
// Layer 1: softmax lanes = slot*8+h; aggregate lane j covers features 2j,2j+1 (head j>>3).
__global__ void gat1_fused(const int* __restrict__ offsets, const int* __restrict__ srcs,
                           const float* __restrict__ el, const float* __restrict__ er,
                           const __bf16* __restrict__ feat1b, const float* __restrict__ b1,
                           __bf16* __restrict__ hbufb) {
    int wave = threadIdx.x >> 6;
    int lane = threadIdx.x & 63;
    int d = blockIdx.x * 4 + wave;
    if (d >= N_NODES) return;
    int off = offsets[d];
    int deg = offsets[d + 1] - off;

    int h = lane & 7, slot = lane >> 3;
    float er_d = er[d * 8 + h];

    float m = NEG_INF, l = 0.f;
    for (int base = 0; base < deg; base += 8) {
        int e = base + slot;
        float sc = NEG_INF;
        if (e < deg) {
            int s = srcs[off + e];
            sc = leaky(el[s * 8 + h] + er_d);
        }
        float mn = fmaxf(m, sc);
        float f1 = (m  == NEG_INF) ? 0.f : __expf(m - mn);
        float f2 = (sc == NEG_INF) ? 0.f : __expf(sc - mn);
        l = l * f1 + f2;
        m = mn;
    }
    #pragma unroll
    for (int mask = 8; mask <= 32; mask <<= 1) {
        float m2 = __shfl_xor(m, mask, 64);
        float l2 = __shfl_xor(l, mask, 64);
        float mn = fmaxf(m, m2);
        float f1 = (m  == NEG_INF) ? 0.f : __expf(m - mn);
        float f2 = (m2 == NEG_INF) ? 0.f : __expf(m2 - mn);
        l = l * f1 + l2 * f2;
        m = mn;
    }
    float inv_l = 1.f / (l + 1e-9f);

    int myh = lane >> 3;   // head for features 2*lane, 2*lane+1
    float acc0 = 0.f, acc1 = 0.f;
    for (int base = 0; base < deg; base += 8) {
        int e = base + slot;
        float alpha = 0.f;
        int s = 0;
        if (e < deg) {
            s = srcs[off + e];
            float sc = leaky(el[s * 8 + h] + er_d);
            alpha = __expf(sc - m) * inv_l;
        }
        int kmax = min(8, deg - base);
        for (int k = 0; k < kmax; ++k) {
            float a  = __shfl(alpha, k * 8 + myh, 64);
            int   se = __shfl(s,     k * 8,       64);
            bf16x2 p = *(const bf16x2*)(feat1b + (size_t)se * F1 + 2 * lane);
            acc0 += a * (float)p.x;
            acc1 += a * (float)p.y;
        }
    }
    float v0 = acc0 + b1[2 * lane];
    float v1 = acc1 + b1[2 * lane + 1];
    v0 = v0 > 0.f ? v0 : expm1f(v0);
    v1 = v1 > 0.f ? v1 : expm1f(v1);
    hbufb[(size_t)d * F1 + 2 * lane]     = (__bf16)v0;
    hbufb[(size_t)d * F1 + 2 * lane + 1] = (__bf16)v1;
}

// Layer 2: 1 head, 40 classes (fp32 feat2)
__global__ void gat2_fused(const int* __restrict__ offsets, const int* __restrict__ srcs,
                           const float* __restrict__ el, const float* __restrict__ er,
                           const float* __restrict__ feat2, const float* __restrict__ b2,
                           float* __restrict__ out) {
    int wave = threadIdx.x >> 6;
    int lane = threadIdx.x & 63;
    int d = blockIdx.x * 4 + wave;
    if (d >= N_NODES) return;
    int off = offsets[d];
    int deg = offsets[d + 1] - off;

    float er_d = er[d];

    float m = NEG_INF, l = 0.f;
    for (int base = 0; base < deg; base += 64) {
        int e = base + lane;
        float sc = NEG_INF;
        if (e < deg) {
            int s = srcs[off + e];
            sc = leaky(el[s] + er_d);
        }
        float mn = fmaxf(m, sc);
        float f1 = (m  == NEG_INF) ? 0.f : __expf(m - mn);
        float f2 = (sc == NEG_INF) ? 0.f : __expf(sc - mn);
        l = l * f1 + f2;
        m = mn;
    }
    #pragma unroll
    for (int mask = 1; mask <= 32; mask <<= 1) {
        float m2 = __shfl_xor(m, mask, 64);
        float l2 = __shfl_xor(l, mask, 64);
        float mn = fmaxf(m, m2);
        float f1 = (m  == NEG_INF) ? 0.f : __expf(m - mn);
        float f2 = (m2 == NEG_INF) ? 0.f : __expf(m2 - mn);
        l = l * f1 + l2 * f2;
        m = mn;
    }
    float inv_l = 1.f / (l + 1e-9f);

    float acc = 0.f;
    for (int base = 0; base < deg; base += 64) {
        int e = base + lane;
        float alpha = 0.f;
        int s = 0;
        if (e < deg) {
            s = srcs[off + e];
            float sc = leaky(el[s] + er_d);
            alpha = __expf(sc - m) * inv_l;
        }
        int kmax = min(64, deg - base);
        for (int k = 0; k < kmax; ++k) {
            float a  = __shfl(alpha, k, 64);
            int   se = __shfl(s,     k, 64);
            if (lane < CLS) acc += a * feat2[(size_t)se * CLS + lane];
        }
    }
    if (lane < CLS) out[(size_t)d * CLS + lane] = acc + b2[lane];
}

// ---------------- launch ----------------
extern "C" void kernel_launch(void* const* d_in, const int* in_sizes, int n_in,
                              void* d_out, int out_size, void* d_ws, size_t ws_size,
                              hipStream_t stream) {
    const float* features = (const float*)d_in[0];
    const int*   esrc     = (const int*)d_in[1];
    const int*   edst     = (const int*)d_in[2];
    const float* W1       = (const float*)d_in[3];
    const float* al1      = (const float*)d_in[4];
    const float* ar1      = (const float*)d_in[5];
    const float* b1       = (const float*)d_in[6];
    const float* W2       = (const float*)d_in[7];
    const float* al2      = (const float*)d_in[8];
    const float* ar2      = (const float*)d_in[9];
    const float* b2       = (const float*)d_in[10];
    float* out = (float*)d_out;

    float* ws = (float*)d_ws;
    float* feat2   = ws;                       // 2,000,000 fp32
    float* el1     = ws + 2000000;             // 400,000
    float* er1     = ws + 2400000;             // 400,000
    float* el2     = ws + 2800000;             // 50,000
    float* er2     = ws + 2850000;             // 50,000
    int*   counts  = (int*)(ws + 2900000);     // 50,000
    int*   cursor  = (int*)(ws + 2950000);     // 50,000 (adjacent for joint zero)
    int*   offsets = (int*)(ws + 3000000);     // 50,001
    int*   bsum    = (int*)(ws + 3060000);     // 256
    int*   bpref   = (int*)(ws + 3061000);     // 256
    int*   srcs    = (int*)(ws + 3062000);     // 800,000
    __bf16* featb  = (__bf16*)(ws + 3900000);  // 6,400,000 bf16 (features)
    __bf16* feat1b = (__bf16*)(ws + 7100000);  // 6,400,000 bf16 (layer1 feat)
    __bf16* hbufb  = (__bf16*)(ws + 10300000); // 6,400,000 bf16 (h)
    __bf16* w1t    = (__bf16*)(ws + 13500000); // 16,384
    __bf16* w2t    = (__bf16*)(ws + 13510000); // 6,144
    // total ~13.52M floats = 54 MB

    const int B = 256;
    const int NB = (N_NODES + 255) / 256;

    // CSR build
    zero_int_kernel<<<(100000 + B - 1) / B, B, 0, stream>>>(counts, 100000);
    hist_kernel<<<(N_EDGES + B - 1) / B, B, 0, stream>>>(edst, counts);
    reduce_kernel<<<NB, 256, 0, stream>>>(counts, bsum);
    scanb_kernel<<<1, 256, 0, stream>>>(bsum, bpref, NB);
    scan_kernel<<<NB, 256, 0, stream>>>(counts, bpref, offsets);
    scatter_kernel<<<(N_EDGES + B - 1) / B, B, 0, stream>>>(esrc, edst, offsets, cursor, srcs);

    // conversions
    conv_feat_kernel<<<(N_NODES * IN_F / 4 + B - 1) / B, B, 0, stream>>>(features, featb);
    conv_w1t_kernel<<<(128 * 128 + B - 1) / B, B, 0, stream>>>(W1, w1t);
    conv_w2t_kernel<<<(48 * 128 + B - 1) / B, B, 0, stream>>>(W2, w2t);

    // layer 1
    gemm1_mfma<<<(N_NODES + 63) / 64, 256, 0, stream>>>(featb, w1t, feat1b);
    elr1_kernel<<<(N_NODES * HEADS + B - 1) / B, B, 0, stream>>>(feat1b, al1, ar1, el1, er1);
    gat1_fused<<<(N_NODES + 3) / 4, B, 0, stream>>>(offsets, srcs, el1, er1, feat1b, b1, hbufb);

    // layer 2
    gemm2_mfma<<<(N_NODES + 63) / 64, 256, 0, stream>>>(hbufb, w2t, feat2);
    elr2_kernel<<<(N_NODES + B - 1) / B, B, 0, stream>>>(feat2, al2, ar2, el2, er2);
    gat2_fused<<<(N_NODES + 3) / 4, B, 0, stream>>>(offsets, srcs, el2, er2, feat2, b2, out);
}

// Round 5
// 315.208 us; speedup vs baseline: 2.9107x; 1.1716x over previous
//
#include <hip/hip_runtime.h>
#include <hip/hip_bf16.h>

#define N_NODES 50000
#define N_EDGES 800000
#define IN_F    128
#define HID     16
#define HEADS   8
#define F1      128   // HEADS*HID
#define CLS     40
#define CLSP    64    // padded feat2 stride
#define NEG     0.2f
#define NEG_INF (-__builtin_inff())

typedef __bf16 bf16x8 __attribute__((ext_vector_type(8)));
typedef float  f32x4  __attribute__((ext_vector_type(4)));

__device__ __forceinline__ float leaky(float v) { return v >= 0.0f ? v : NEG * v; }

// ---------------- CSR build ----------------
__global__ void zero_int_kernel(int* __restrict__ p, int n) {
    int i = blockIdx.x * blockDim.x + threadIdx.x;
    if (i < n) p[i] = 0;
}

__global__ void hist_kernel(const int* __restrict__ dst, int* __restrict__ counts) {
    int e = blockIdx.x * blockDim.x + threadIdx.x;
    if (e < N_EDGES) atomicAdd(&counts[dst[e]], 1);
}

__global__ void reduce_kernel(const int* __restrict__ counts, int* __restrict__ bsum) {
    __shared__ int sm[256];
    int t = threadIdx.x;
    int i = blockIdx.x * 256 + t;
    sm[t] = (i < N_NODES) ? counts[i] : 0;
    __syncthreads();
    for (int off = 128; off > 0; off >>= 1) {
        if (t < off) sm[t] += sm[t + off];
        __syncthreads();
    }
    if (t == 0) bsum[blockIdx.x] = sm[0];
}

__global__ void scanb_kernel(const int* __restrict__ bsum, int* __restrict__ bpref, int nb) {
    __shared__ int sm[256];
    int t = threadIdx.x;
    int x = (t < nb) ? bsum[t] : 0;
    sm[t] = x;
    __syncthreads();
    for (int off = 1; off < 256; off <<= 1) {
        int v = (t >= off) ? sm[t - off] : 0;
        __syncthreads();
        sm[t] += v;
        __syncthreads();
    }
    bpref[t] = sm[t] - x;   // exclusive
}

__global__ void scan_kernel(const int* __restrict__ counts, const int* __restrict__ bpref,
                            int* __restrict__ offsets) {
    __shared__ int sm[256];
    int t = threadIdx.x;
    int i = blockIdx.x * 256 + t;
    int x = (i < N_NODES) ? counts[i] : 0;
    sm[t] = x;
    __syncthreads();
    for (int off = 1; off < 256; off <<= 1) {
        int v = (t >= off) ? sm[t - off] : 0;
        __syncthreads();
        sm[t] += v;
        __syncthreads();
    }
    if (i <= N_NODES) offsets[i] = bpref[blockIdx.x] + sm[t] - x;
}

__global__ void scatter_kernel(const int* __restrict__ src, const int* __restrict__ dst,
                               const int* __restrict__ offsets, int* __restrict__ cursor,
                               int* __restrict__ srcs_sorted) {
    int e = blockIdx.x * blockDim.x + threadIdx.x;
    if (e >= N_EDGES) return;
    int d = dst[e];
    int pos = offsets[d] + atomicAdd(&cursor[d], 1);
    srcs_sorted[pos] = src[e];
}

// ---------------- weight conversion ----------------
// W1[k][n] (128x128) -> w1t[n][k] bf16
__global__ void conv_w1t_kernel(const float* __restrict__ W1, __bf16* __restrict__ w1t) {
    int i = blockIdx.x * blockDim.x + threadIdx.x;
    if (i >= 128 * 128) return;
    int n = i >> 7, k = i & 127;
    w1t[i] = (__bf16)W1[k * 128 + n];
}

// W2[k][c] (128x40) -> w2t[n][k] bf16 padded to n<64
__global__ void conv_w2t_kernel(const float* __restrict__ W2, __bf16* __restrict__ w2t) {
    int i = blockIdx.x * blockDim.x + threadIdx.x;
    if (i >= 64 * 128) return;
    int n = i >> 7, k = i & 127;
    w2t[i] = (n < CLS) ? (__bf16)W2[k * CLS + n] : (__bf16)0.0f;
}

// ---------------- MFMA GEMMs ----------------
// features fp32 [N,128] @ w1t -> feat1b[N,128] bf16 (conversion fused).
__global__ __launch_bounds__(256) void gemm1_mfma(const float* __restrict__ A,
                                                  const __bf16* __restrict__ Wt,
                                                  __bf16* __restrict__ outb) {
    int wave = threadIdx.x >> 6, lane = threadIdx.x & 63;
    int m0 = blockIdx.x * 64 + wave * 16;
    int row = m0 + (lane & 15);
    int rowc = row < N_NODES ? row : N_NODES - 1;   // clamped read; writes guarded
    int ko = (lane >> 4) * 8;

    f32x4 acc[8];
    #pragma unroll
    for (int t = 0; t < 8; ++t)
        #pragma unroll
        for (int r = 0; r < 4; ++r) acc[t][r] = 0.f;

    for (int ks = 0; ks < 128; ks += 32) {
        const float* ap = A + (size_t)rowc * 128 + ks + ko;
        float4 u = *(const float4*)ap;
        float4 v = *(const float4*)(ap + 4);
        bf16x8 a;
        a[0] = (__bf16)u.x; a[1] = (__bf16)u.y; a[2] = (__bf16)u.z; a[3] = (__bf16)u.w;
        a[4] = (__bf16)v.x; a[5] = (__bf16)v.y; a[6] = (__bf16)v.z; a[7] = (__bf16)v.w;
        #pragma unroll
        for (int t = 0; t < 8; ++t) {
            bf16x8 b = *(const bf16x8*)(Wt + (size_t)(t * 16 + (lane & 15)) * 128 + ks + ko);
            acc[t] = __builtin_amdgcn_mfma_f32_16x16x32_bf16(a, b, acc[t], 0, 0, 0);
        }
    }
    int rbase = m0 + (lane >> 4) * 4;
    #pragma unroll
    for (int t = 0; t < 8; ++t) {
        int gcol = t * 16 + (lane & 15);
        #pragma unroll
        for (int r = 0; r < 4; ++r) {
            int grow = rbase + r;
            if (grow < N_NODES) outb[(size_t)grow * 128 + gcol] = (__bf16)acc[t][r];
        }
    }
}

// hbufb[N,128]bf16 @ w2t(64x128) -> feat2p[N,64] fp32 (cols 40..63 = 0)
__global__ __launch_bounds__(256) void gemm2_mfma(const __bf16* __restrict__ A,
                                                  const __bf16* __restrict__ Wt,
                                                  float* __restrict__ out) {
    int wave = threadIdx.x >> 6, lane = threadIdx.x & 63;
    int m0 = blockIdx.x * 64 + wave * 16;
    int row = m0 + (lane & 15);
    int rowc = row < N_NODES ? row : N_NODES - 1;
    int ko = (lane >> 4) * 8;

    f32x4 acc[4];
    #pragma unroll
    for (int t = 0; t < 4; ++t)
        #pragma unroll
        for (int r = 0; r < 4; ++r) acc[t][r] = 0.f;

    for (int ks = 0; ks < 128; ks += 32) {
        bf16x8 a = *(const bf16x8*)(A + (size_t)rowc * 128 + ks + ko);
        #pragma unroll
        for (int t = 0; t < 4; ++t) {
            bf16x8 b = *(const bf16x8*)(Wt + (size_t)(t * 16 + (lane & 15)) * 128 + ks + ko);
            acc[t] = __builtin_amdgcn_mfma_f32_16x16x32_bf16(a, b, acc[t], 0, 0, 0);
        }
    }
    int rbase = m0 + (lane >> 4) * 4;
    #pragma unroll
    for (int t = 0; t < 4; ++t) {
        int gcol = t * 16 + (lane & 15);
        #pragma unroll
        for (int r = 0; r < 4; ++r) {
            int grow = rbase + r;
            if (grow < N_NODES) out[(size_t)grow * CLSP + gcol] = acc[t][r];
        }
    }
}

// ---------------- attention dot products ----------------
__global__ void elr1_kernel(const __bf16* __restrict__ feat1b,
                            const float* __restrict__ al, const float* __restrict__ ar,
                            float* __restrict__ el, float* __restrict__ er) {
    int idx = blockIdx.x * blockDim.x + threadIdx.x;
    if (idx >= N_NODES * HEADS) return;
    int n = idx >> 3, h = idx & 7;
    const __bf16* f = feat1b + (size_t)n * F1 + h * HID;
    float a = 0.f, b = 0.f;
    #pragma unroll
    for (int d = 0; d < HID; ++d) {
        float v = (float)f[d];
        a += v * al[h * HID + d];
        b += v * ar[h * HID + d];
    }
    el[idx] = a;
    er[idx] = b;
}

__global__ void elr2_kernel(const float* __restrict__ feat2p,
                            const float* __restrict__ al, const float* __restrict__ ar,
                            float* __restrict__ el, float* __restrict__ er) {
    int n = blockIdx.x * blockDim.x + threadIdx.x;
    if (n >= N_NODES) return;
    const float* f = feat2p + (size_t)n * CLSP;
    float a = 0.f, b = 0.f;
    #pragma unroll
    for (int c = 0; c < CLS; ++c) {
        a += f[c] * al[c];
        b += f[c] * ar[c];
    }
    el[n] = a;
    er[n] = b;
}

// ---------------- fused GAT layers ----------------
// Layer 1. Softmax phase: lane = slot*8 + h (8 edge slots x 8 heads).
// Aggregate phase: q = lane>>4 (edge sub-slot, 4 edges/iter), fg = lane&15
// (feature group: features fg*8..fg*8+7, head fg>>1), bf16x8 (16B) loads.
__global__ void gat1_fused(const int* __restrict__ offsets, const int* __restrict__ srcs,
                           const float* __restrict__ el, const float* __restrict__ er,
                           const __bf16* __restrict__ feat1b, const float* __restrict__ b1,
                           __bf16* __restrict__ hbufb) {
    int wave = threadIdx.x >> 6;
    int lane = threadIdx.x & 63;
    int d = blockIdx.x * 4 + wave;
    if (d >= N_NODES) return;
    int off = offsets[d];
    int deg = offsets[d + 1] - off;

    int h = lane & 7, slot = lane >> 3;
    float er_d = er[d * 8 + h];

    float m = NEG_INF, l = 0.f;
    for (int base = 0; base < deg; base += 8) {
        int e = base + slot;
        float sc = NEG_INF;
        if (e < deg) {
            int s = srcs[off + e];
            sc = leaky(el[s * 8 + h] + er_d);
        }
        float mn = fmaxf(m, sc);
        float f1 = (m  == NEG_INF) ? 0.f : __expf(m - mn);
        float f2 = (sc == NEG_INF) ? 0.f : __expf(sc - mn);
        l = l * f1 + f2;
        m = mn;
    }
    #pragma unroll
    for (int mask = 8; mask <= 32; mask <<= 1) {
        float m2 = __shfl_xor(m, mask, 64);
        float l2 = __shfl_xor(l, mask, 64);
        float mn = fmaxf(m, m2);
        float f1 = (m  == NEG_INF) ? 0.f : __expf(m - mn);
        float f2 = (m2 == NEG_INF) ? 0.f : __expf(m2 - mn);
        l = l * f1 + l2 * f2;
        m = mn;
    }
    float inv_l = 1.f / (l + 1e-9f);

    int q  = lane >> 4;
    int fg = lane & 15;
    int hd = fg >> 1;
    float acc[8];
    #pragma unroll
    for (int i = 0; i < 8; ++i) acc[i] = 0.f;

    for (int base = 0; base < deg; base += 8) {
        int e = base + slot;
        float alpha = 0.f;
        int s = 0;
        if (e < deg) {
            s = srcs[off + e];
            float sc = leaky(el[s * 8 + h] + er_d);
            alpha = __expf(sc - m) * inv_l;
        }
        #pragma unroll
        for (int sub = 0; sub < 2; ++sub) {
            int k = sub * 4 + q;                       // edge slot within 8-group
            float a  = __shfl(alpha, k * 8 + hd, 64);  // alpha=0 for e>=deg slots
            int   se = __shfl(s,     k * 8,      64);
            bf16x8 p = *(const bf16x8*)(feat1b + (size_t)se * F1 + fg * 8);
            #pragma unroll
            for (int i = 0; i < 8; ++i) acc[i] += a * (float)p[i];
        }
    }
    #pragma unroll
    for (int i = 0; i < 8; ++i) {
        acc[i] += __shfl_xor(acc[i], 16, 64);
        acc[i] += __shfl_xor(acc[i], 32, 64);
    }
    if (q == 0) {
        bf16x8 o;
        #pragma unroll
        for (int i = 0; i < 8; ++i) {
            float v = acc[i] + b1[fg * 8 + i];
            v = v > 0.f ? v : expm1f(v);
            o[i] = (__bf16)v;
        }
        *(bf16x8*)(hbufb + (size_t)d * F1 + fg * 8) = o;
    }
}

// Layer 2. Softmax: lane = edge slot. Aggregate: q=lane>>4 (4 edges/iter),
// cg=lane&15 (classes cg*4..cg*4+3 of padded-64 feat2p), float4 loads.
__global__ void gat2_fused(const int* __restrict__ offsets, const int* __restrict__ srcs,
                           const float* __restrict__ el, const float* __restrict__ er,
                           const float* __restrict__ feat2p, const float* __restrict__ b2,
                           float* __restrict__ out) {
    int wave = threadIdx.x >> 6;
    int lane = threadIdx.x & 63;
    int d = blockIdx.x * 4 + wave;
    if (d >= N_NODES) return;
    int off = offsets[d];
    int deg = offsets[d + 1] - off;

    float er_d = er[d];

    float m = NEG_INF, l = 0.f;
    for (int base = 0; base < deg; base += 64) {
        int e = base + lane;
        float sc = NEG_INF;
        if (e < deg) {
            int s = srcs[off + e];
            sc = leaky(el[s] + er_d);
        }
        float mn = fmaxf(m, sc);
        float f1 = (m  == NEG_INF) ? 0.f : __expf(m - mn);
        float f2 = (sc == NEG_INF) ? 0.f : __expf(sc - mn);
        l = l * f1 + f2;
        m = mn;
    }
    #pragma unroll
    for (int mask = 1; mask <= 32; mask <<= 1) {
        float m2 = __shfl_xor(m, mask, 64);
        float l2 = __shfl_xor(l, mask, 64);
        float mn = fmaxf(m, m2);
        float f1 = (m  == NEG_INF) ? 0.f : __expf(m - mn);
        float f2 = (m2 == NEG_INF) ? 0.f : __expf(m2 - mn);
        l = l * f1 + l2 * f2;
        m = mn;
    }
    float inv_l = 1.f / (l + 1e-9f);

    int q  = lane >> 4;
    int cg = lane & 15;
    float acc[4];
    #pragma unroll
    for (int i = 0; i < 4; ++i) acc[i] = 0.f;

    for (int base = 0; base < deg; base += 64) {
        int e = base + lane;
        float alpha = 0.f;
        int s = 0;
        if (e < deg) {
            s = srcs[off + e];
            float sc = leaky(el[s] + er_d);
            alpha = __expf(sc - m) * inv_l;
        }
        int kmax = min(64, deg - base);
        int nsub = (kmax + 3) >> 2;
        for (int sub = 0; sub < nsub; ++sub) {
            int k = sub * 4 + q;
            float a  = __shfl(alpha, k, 64);   // alpha=0 for k>=kmax
            int   se = __shfl(s,     k, 64);
            float4 p = *(const float4*)(feat2p + (size_t)se * CLSP + cg * 4);
            acc[0] += a * p.x; acc[1] += a * p.y; acc[2] += a * p.z; acc[3] += a * p.w;
        }
    }
    #pragma unroll
    for (int i = 0; i < 4; ++i) {
        acc[i] += __shfl_xor(acc[i], 16, 64);
        acc[i] += __shfl_xor(acc[i], 32, 64);
    }
    if (lane < 10) {   // q==0, cg<10: classes cg*4..cg*4+3
        float4 o;
        o.x = acc[0] + b2[cg * 4 + 0];
        o.y = acc[1] + b2[cg * 4 + 1];
        o.z = acc[2] + b2[cg * 4 + 2];
        o.w = acc[3] + b2[cg * 4 + 3];
        *(float4*)(out + (size_t)d * CLS + cg * 4) = o;
    }
}

// ---------------- launch ----------------
extern "C" void kernel_launch(void* const* d_in, const int* in_sizes, int n_in,
                              void* d_out, int out_size, void* d_ws, size_t ws_size,
                              hipStream_t stream) {
    const float* features = (const float*)d_in[0];
    const int*   esrc     = (const int*)d_in[1];
    const int*   edst     = (const int*)d_in[2];
    const float* W1       = (const float*)d_in[3];
    const float* al1      = (const float*)d_in[4];
    const float* ar1      = (const float*)d_in[5];
    const float* b1       = (const float*)d_in[6];
    const float* W2       = (const float*)d_in[7];
    const float* al2      = (const float*)d_in[8];
    const float* ar2      = (const float*)d_in[9];
    const float* b2       = (const float*)d_in[10];
    float* out = (float*)d_out;

    float* ws = (float*)d_ws;
    float* feat2p  = ws;                       // 3,200,000 fp32 (N x 64 padded)
    float* el1     = ws + 3200000;             // 400,000
    float* er1     = ws + 3600000;             // 400,000
    float* el2     = ws + 4000000;             // 50,000
    float* er2     = ws + 4050000;             // 50,000
    int*   counts  = (int*)(ws + 4100000);     // 50,000
    int*   cursor  = (int*)(ws + 4150000);     // 50,000 (adjacent for joint zero)
    int*   offsets = (int*)(ws + 4200000);     // 50,001
    int*   bsum    = (int*)(ws + 4260000);     // 256
    int*   bpref   = (int*)(ws + 4261000);     // 256
    int*   srcs    = (int*)(ws + 4262000);     // 800,000
    __bf16* feat1b = (__bf16*)(ws + 5100000);  // 6,400,000 bf16
    __bf16* hbufb  = (__bf16*)(ws + 8300000);  // 6,400,000 bf16
    __bf16* w1t    = (__bf16*)(ws + 11500000); // 16,384 bf16
    __bf16* w2t    = (__bf16*)(ws + 11510000); // 8,192 bf16
    // total ~11.52M floats = 46 MB

    const int B = 256;
    const int NB = (N_NODES + 255) / 256;

    // CSR build
    zero_int_kernel<<<(100000 + B - 1) / B, B, 0, stream>>>(counts, 100000);
    hist_kernel<<<(N_EDGES + B - 1) / B, B, 0, stream>>>(edst, counts);
    reduce_kernel<<<NB, 256, 0, stream>>>(counts, bsum);
    scanb_kernel<<<1, 256, 0, stream>>>(bsum, bpref, NB);
    scan_kernel<<<NB, 256, 0, stream>>>(counts, bpref, offsets);
    scatter_kernel<<<(N_EDGES + B - 1) / B, B, 0, stream>>>(esrc, edst, offsets, cursor, srcs);

    // weight conversions
    conv_w1t_kernel<<<(128 * 128 + B - 1) / B, B, 0, stream>>>(W1, w1t);
    conv_w2t_kernel<<<(64 * 128 + B - 1) / B, B, 0, stream>>>(W2, w2t);

    // layer 1
    gemm1_mfma<<<(N_NODES + 63) / 64, 256, 0, stream>>>(features, w1t, feat1b);
    elr1_kernel<<<(N_NODES * HEADS + B - 1) / B, B, 0, stream>>>(feat1b, al1, ar1, el1, er1);
    gat1_fused<<<(N_NODES + 3) / 4, B, 0, stream>>>(offsets, srcs, el1, er1, feat1b, b1, hbufb);

    // layer 2
    gemm2_mfma<<<(N_NODES + 63) / 64, 256, 0, stream>>>(hbufb, w2t, feat2p);
    elr2_kernel<<<(N_NODES + B - 1) / B, B, 0, stream>>>(feat2p, al2, ar2, el2, er2);
    gat2_fused<<<(N_NODES + 3) / 4, B, 0, stream>>>(offsets, srcs, el2, er2, feat2p, b2, out);
}